// Round 4
// baseline (5665.866 us; speedup 1.0000x reference)
//
#include <hip/hip_runtime.h>
#include <hip/hip_bf16.h>
#include <cstdint>
#include <cstddef>

// MultiGateMixExperts: fp16 MFMA GEMMs, frag-major layout.
// Frag-major layout: frag(tile16 t, kchunk32 c) = 1KB at ((t*32+c)*64+lane)*16B;
// lane l holds M[row=t*16+(l&15)][k=c*32+(l>>4)*8 .. +7] (fp16).
// R9: 256x256 tile with the PROVEN R6 loop shape + 2 blocks/CU.
// Evidence: R6 (128^2, 32KB LDS, 2-3 blocks/CU) = 86us/35% MfmaUtil beat
// R7/R8 (256^2, 128KB LDS, 1 block/CU) = 92us/29% despite better reuse and
// counted vmcnt. Within a block every phase is read->wait->MFMA serial;
// overlap comes from OTHER resident blocks. So: keep 256^2 reuse
// (43.7 FLOP/LDS-byte vs 32 for 128^2) but BK=32 -> 2x32KB LDS = 64KB ->
// 2 blocks/CU, and the simple R6 double-buffer loop (1 syncthreads/chunk).
// Per chunk per wave: 4 global_load_lds_dwordx4 (stage) + 12 ds_read_b128 +
// 32 mfma_16x16x32_f16. K-chunk order 0..31 per acc element -> numerics
// identical to R6/R7/R8.
// h1 = sigmoid(x@W1[e]+b1); h2 = relu(h1@W2[e]+b2);
// f = (h2@W2[e]+b2).Wo[e] fused into stage-3 epilogue (atomicAdd over n-blocks)
// out_i = softmax(x@Wg_i+bg_i) . (f+bo)

using half8   = __attribute__((ext_vector_type(8))) _Float16;
using floatx4 = __attribute__((ext_vector_type(4))) float;

// ---------------------------------------------------------------- GEMM ------
// ACT: 0=sigmoid, 1=relu (writes C in frag layout), 2=f-fused (no C store).
// Block 256x256, 8 waves (2M x 4N), wave tile 128x64 (8x4 of 16x16x32).
template<int ACT>
__global__ __launch_bounds__(512, 4)
void gemm_kernel(const _Float16* __restrict__ A, const _Float16* __restrict__ Bt,
                 const float* __restrict__ bias, _Float16* __restrict__ C,
                 size_t a_estride,
                 const float* __restrict__ Wo, float* __restrict__ f, int e0)
{
    // 2 x 32KB k-chunk buffers: halves [0,8192) = A frags (mtl*512),
    // [8192,16384) = B frags (8192 + ntl*512). Lane-linear 1KB frags.
    __shared__ __align__(16) _Float16 sbuf[2][16384];

    const int tid  = threadIdx.x;
    const int lane = tid & 63;
    const int w    = tid >> 6;      // wave 0..7
    const int wm   = w & 1;         // m-half (128 rows)
    const int wn   = w >> 1;        // n-slice 0..3 (64 cols)

    // --- XCD-aware windowed remap (gridDim = {8, 16*g}) ---
    // window = 4 m-blocks x 4 n-blocks per XCD: A-window 2MB + B 2MB ~ L2.
    const int flat = blockIdx.x + (blockIdx.y << 3);
    const int xcd  = flat & 7;
    int s = flat >> 3;
    const int g = gridDim.y >> 4;
    int le, mb_base;
    if (g <= 8) {
        const int p = 8 / g;            // XCDs per expert
        le = xcd / p;
        mb_base = (xcd % p) * (32 / p);
    } else {                            // g == 16
        le = (xcd << 1) | (s >> 7);
        s &= 127;
        mb_base = 0;
    }
    const int nb = (s >> 2) & 3;
    const int mb = mb_base + (s >> 4) * 4 + (s & 3);
    const int m0 = mb * 256;
    const int n0 = nb * 256;

    const _Float16* Ae = A    + (size_t)le * a_estride;
    const _Float16* Be = Bt   + (size_t)le * (1024ull * 1024ull);
    const float*    be = bias + (size_t)le * 1024ull;
    _Float16*       Ce = C    + (size_t)le * (8192ull * 1024ull);

    const int mtb_blk = m0 >> 4;        // block's first A m-tile (16 total)
    const int ntb_blk = n0 >> 4;        // block's first B n-tile (16 total)

    // staging: wave w owns A-frags {2w, 2w+1} and B-frags {2w, 2w+1}.
    // per-lane global src (+lane*16B), advanced 512 halves per chunk.
    const _Float16* gA0 = Ae + (size_t)(mtb_blk + 2 * w)     * (32 * 512) + lane * 8;
    const _Float16* gA1 = Ae + (size_t)(mtb_blk + 2 * w + 1) * (32 * 512) + lane * 8;
    const _Float16* gB0 = Be + (size_t)(ntb_blk + 2 * w)     * (32 * 512) + lane * 8;
    const _Float16* gB1 = Be + (size_t)(ntb_blk + 2 * w + 1) * (32 * 512) + lane * 8;
    const int dA0 = (2 * w) * 512;
    const int dA1 = (2 * w + 1) * 512;
    const int dB0 = 8192 + (2 * w) * 512;
    const int dB1 = 8192 + (2 * w + 1) * 512;

    auto STAGE = [&](int t, _Float16* buf) {
        const size_t o = (size_t)t * 512;
        __builtin_amdgcn_global_load_lds(
            (const __attribute__((address_space(1))) void*)(gA0 + o),
            (__attribute__((address_space(3))) void*)(buf + dA0), 16, 0, 0);
        __builtin_amdgcn_global_load_lds(
            (const __attribute__((address_space(1))) void*)(gA1 + o),
            (__attribute__((address_space(3))) void*)(buf + dA1), 16, 0, 0);
        __builtin_amdgcn_global_load_lds(
            (const __attribute__((address_space(1))) void*)(gB0 + o),
            (__attribute__((address_space(3))) void*)(buf + dB0), 16, 0, 0);
        __builtin_amdgcn_global_load_lds(
            (const __attribute__((address_space(1))) void*)(gB1 + o),
            (__attribute__((address_space(3))) void*)(buf + dB1), 16, 0, 0);
    };

    floatx4 acc[8][4];
#pragma unroll
    for (int i = 0; i < 8; ++i)
#pragma unroll
        for (int j = 0; j < 4; ++j) { floatx4 z = {0.f, 0.f, 0.f, 0.f}; acc[i][j] = z; }

    auto COMPUTE = [&](const _Float16* buf) {
        half8 a[8], b[4];
#pragma unroll
        for (int i = 0; i < 8; ++i)
            a[i] = *(const half8*)(buf + (wm * 8 + i) * 512 + lane * 8);
#pragma unroll
        for (int j = 0; j < 4; ++j)
            b[j] = *(const half8*)(buf + 8192 + (wn * 4 + j) * 512 + lane * 8);
#pragma unroll
        for (int i = 0; i < 8; ++i)
#pragma unroll
            for (int j = 0; j < 4; ++j)
                acc[i][j] = __builtin_amdgcn_mfma_f32_16x16x32_f16(a[i], b[j], acc[i][j], 0, 0, 0);
    };

    // K = 1024 -> 32 chunks of 32. Double-buffered, 1 barrier per chunk.
    // __syncthreads drains vmcnt -> staged chunk ready + WAR-safe buffer swap;
    // the drain stall is covered by the co-resident block (2 blocks/CU).
    STAGE(0, &sbuf[0][0]);
    __syncthreads();
#pragma unroll 1
    for (int c = 0; c < 30; c += 2) {
        STAGE(c + 1, &sbuf[1][0]);
        COMPUTE(&sbuf[0][0]);
        __syncthreads();
        STAGE(c + 2, &sbuf[0][0]);
        COMPUTE(&sbuf[1][0]);
        __syncthreads();
    }
    STAGE(31, &sbuf[1][0]);
    COMPUTE(&sbuf[0][0]);
    __syncthreads();
    COMPUTE(&sbuf[1][0]);

    // ----- epilogue; C/D layout: col=lane&15, row=(lane>>4)*4+r -----
    const int q   = lane >> 4;
    const int l15 = lane & 15;
    float bj[4];
#pragma unroll
    for (int j = 0; j < 4; ++j) bj[j] = be[n0 + (wn * 4 + j) * 16 + l15];

    if (ACT == 2) {
        // f[m, e0+le] += sum_n (acc + b2[n]) * Wo[e0+le, n]
        const float* we = Wo + (size_t)(e0 + le) * 1024;
        float wj[4];
#pragma unroll
        for (int j = 0; j < 4; ++j) wj[j] = we[n0 + (wn * 4 + j) * 16 + l15];
#pragma unroll
        for (int i = 0; i < 8; ++i) {
            const int mbase = m0 + (wm * 8 + i) * 16 + q * 4;
#pragma unroll
            for (int r = 0; r < 4; ++r) {
                float sacc = 0.f;
#pragma unroll
                for (int j = 0; j < 4; ++j) sacc += (acc[i][j][r] + bj[j]) * wj[j];
#pragma unroll
                for (int m = 1; m < 16; m <<= 1) sacc += __shfl_xor(sacc, m, 64);
                if (l15 == 0) atomicAdd(&f[(size_t)(mbase + r) * 16 + (e0 + le)], sacc);
            }
        }
    } else {
        // per-wave repack (private 1024-half region of sbuf[0]; no barrier
        // needed: last COMPUTE read sbuf[1] only, and the last read of
        // sbuf[0] was fenced by the final in-loop __syncthreads).
        _Float16* T = &sbuf[0][0] + w * 1024;
        const int kcb = (n0 >> 5) + wn * 2;
#pragma unroll
        for (int i = 0; i < 8; ++i) {
            const int mtg = mtb_blk + wm * 8 + i;
#pragma unroll
            for (int jp = 0; jp < 2; ++jp) {
#pragma unroll
                for (int j2 = 0; j2 < 2; ++j2) {
                    const int j = jp * 2 + j2;
#pragma unroll
                    for (int r = 0; r < 4; ++r) {
                        float v = acc[i][j][r] + bj[j];
                        if (ACT == 0) v = 1.0f / (1.0f + __expf(-v));
                        else          v = fmaxf(v, 0.0f);
                        T[(q * 4 + r) * 40 + j2 * 16 + l15] = (_Float16)v;
                    }
                }
                half8 v8 = *(const half8*)(T + l15 * 40 + q * 8);
                *(half8*)(Ce + ((size_t)mtg * 32 + kcb + jp) * 512 + lane * 8) = v8;
            }
        }
    }
}

// --------------------------------------- cast x to fp16 frag layout ---------
__global__ __launch_bounds__(256)
void castx_kernel(const float* __restrict__ x, _Float16* __restrict__ xb)
{
    __shared__ _Float16 tile[64 * 72];   // [m-local][k-local]
    const int k0 = blockIdx.x * 64;
    const int m0 = blockIdx.y * 64;
    const int tid = threadIdx.x;
    const int col4 = (tid & 15) * 4;
    const int rb   = tid >> 4;           // 0..15
#pragma unroll
    for (int p = 0; p < 4; ++p) {
        const int row = rb + p * 16;
        float4 a = *(const float4*)(x + (size_t)(m0 + row) * 1024 + k0 + col4);
        _Float16* d = tile + row * 72 + col4;
        d[0] = (_Float16)a.x; d[1] = (_Float16)a.y; d[2] = (_Float16)a.z; d[3] = (_Float16)a.w;
    }
    __syncthreads();
    const int lane = tid & 63, w = tid >> 6;
    const int l15 = lane & 15, q = lane >> 4;
#pragma unroll
    for (int ff = 0; ff < 2; ++ff) {
        const int fidx = w * 2 + ff;
        const int mi = fidx >> 1, kci = fidx & 1;
        half8 v = *(const half8*)(tile + (mi * 16 + l15) * 72 + kci * 32 + q * 8);
        const size_t mt = (m0 >> 4) + mi, kc = (k0 >> 5) + kci;
        *(half8*)(xb + (mt * 32 + kc) * 512 + lane * 8) = v;
    }
}

// ------------------- W1/W2 [d][h] fp32 -> frag-major fp16 (n=h, k=d) --------
__global__ __launch_bounds__(256)
void wtr_kernel(const float* __restrict__ W1, const float* __restrict__ W2,
                _Float16* __restrict__ W1F, _Float16* __restrict__ W2F)
{
    __shared__ _Float16 tile[64 * 73];   // [k-local][n-local], pad 73
    const int z = blockIdx.z;
    const float* src = (z < 16) ? (W1 + (size_t)z * 1048576ull) : (W2 + (size_t)(z - 16) * 1048576ull);
    _Float16*    dst = (z < 16) ? (W1F + (size_t)z * 1048576ull) : (W2F + (size_t)(z - 16) * 1048576ull);
    const int n0 = blockIdx.x * 64;
    const int k0 = blockIdx.y * 64;
    const int tid = threadIdx.x;
    const int col = tid & 63;
    const int rb  = tid >> 6;            // 0..3
#pragma unroll
    for (int p = 0; p < 16; ++p) {
        const int row = rb * 16 + p;
        tile[row * 73 + col] = (_Float16)src[(size_t)(k0 + row) * 1024 + n0 + col];
    }
    __syncthreads();
    const int lane = tid & 63, w = tid >> 6;
    const int l15 = lane & 15, q = lane >> 4;
#pragma unroll
    for (int ff = 0; ff < 2; ++ff) {
        const int fidx = w * 2 + ff;
        const int nti = fidx >> 1, kci = fidx & 1;
        half8 v;
#pragma unroll
        for (int jj = 0; jj < 8; ++jj)
            v[jj] = tile[(kci * 32 + q * 8 + jj) * 73 + nti * 16 + l15];
        const size_t nt = (n0 >> 4) + nti, kc = (k0 >> 5) + kci;
        *(half8*)(dst + (nt * 32 + kc) * 512 + lane * 8) = v;
    }
}

// ---------------------------------------------------- zero f ----------------
__global__ __launch_bounds__(256)
void zerof_kernel(float* __restrict__ f)
{
    const size_t i = ((size_t)blockIdx.x * 256 + threadIdx.x) * 4;
    float4 z = {0.f, 0.f, 0.f, 0.f};
    *(float4*)(f + i) = z;
}

// ------------------ gates (fp32, full precision) + softmax + combine --------
__global__ __launch_bounds__(256)
void final_kernel(const float* __restrict__ x,
                  const float* __restrict__ Wg1, const float* __restrict__ bg1,
                  const float* __restrict__ Wg2, const float* __restrict__ bg2,
                  const float* __restrict__ f, const float* __restrict__ bo,
                  float* __restrict__ out)
{
    const int lane = threadIdx.x & 63;
    const int w    = threadIdx.x >> 6;
    const int b    = blockIdx.x * 8 + w * 2;
    const float* xA = x + (size_t)b * 1024;
    const float* xB = xA + 1024;
    float g1A[16], g2A[16], g1B[16], g2B[16];
#pragma unroll
    for (int e = 0; e < 16; ++e) { g1A[e] = 0.f; g2A[e] = 0.f; g1B[e] = 0.f; g2B[e] = 0.f; }
#pragma unroll 2
    for (int t = 0; t < 16; ++t) {
        const int d = t * 64 + lane;
        const float xa = xA[d];
        const float xb2 = xB[d];
        const float4* w1 = (const float4*)(Wg1 + (size_t)d * 16);
        const float4* w2 = (const float4*)(Wg2 + (size_t)d * 16);
#pragma unroll
        for (int q4 = 0; q4 < 4; ++q4) {
            const float4 c1 = w1[q4];
            const float4 c2 = w2[q4];
#pragma unroll
            for (int c = 0; c < 4; ++c) {
                const int e = q4 * 4 + c;
                const float v1 = (c == 0) ? c1.x : (c == 1) ? c1.y : (c == 2) ? c1.z : c1.w;
                const float v2 = (c == 0) ? c2.x : (c == 1) ? c2.y : (c == 2) ? c2.z : c2.w;
                g1A[e] += xa * v1; g1B[e] += xb2 * v1;
                g2A[e] += xa * v2; g2B[e] += xb2 * v2;
            }
        }
    }
#pragma unroll
    for (int e = 0; e < 16; ++e) {
#pragma unroll
        for (int m = 1; m < 64; m <<= 1) {
            g1A[e] += __shfl_xor(g1A[e], m, 64);
            g2A[e] += __shfl_xor(g2A[e], m, 64);
            g1B[e] += __shfl_xor(g1B[e], m, 64);
            g2B[e] += __shfl_xor(g2B[e], m, 64);
        }
    }
    const float* fbA = f + (size_t)b * 16;
    const float* fbB = fbA + 16;
#pragma unroll
    for (int rr = 0; rr < 2; ++rr) {
        const float* gp1 = rr ? g1B : g1A;
        const float* gp2 = rr ? g2B : g2A;
        const float* fb  = rr ? fbB : fbA;
        float a1[16], a2[16], m1 = -1e30f, m2 = -1e30f;
#pragma unroll
        for (int e = 0; e < 16; ++e) {
            a1[e] = gp1[e] + bg1[e]; m1 = fmaxf(m1, a1[e]);
            a2[e] = gp2[e] + bg2[e]; m2 = fmaxf(m2, a2[e]);
        }
        float s1 = 0.f, s2 = 0.f, o1 = 0.f, o2 = 0.f;
#pragma unroll
        for (int e = 0; e < 16; ++e) {
            a1[e] = __expf(a1[e] - m1); s1 += a1[e];
            a2[e] = __expf(a2[e] - m2); s2 += a2[e];
        }
#pragma unroll
        for (int e = 0; e < 16; ++e) {
            const float fe = fb[e] + bo[e];
            o1 += a1[e] * fe; o2 += a2[e] * fe;
        }
        if (lane == 0) { out[b + rr] = o1 / s1; out[8192 + b + rr] = o2 / s2; }
    }
}

// ----------------------------------------------------------------------------
extern "C" void kernel_launch(void* const* d_in, const int* in_sizes, int n_in,
                              void* d_out, int out_size, void* d_ws, size_t ws_size,
                              hipStream_t stream)
{
    const float* x   = (const float*)d_in[0];
    const float* W1  = (const float*)d_in[1];
    const float* b1  = (const float*)d_in[2];
    const float* W2  = (const float*)d_in[3];
    const float* b2  = (const float*)d_in[4];
    const float* Wo  = (const float*)d_in[5];
    const float* bo  = (const float*)d_in[6];
    const float* Wg1 = (const float*)d_in[7];
    const float* bg1 = (const float*)d_in[8];
    const float* Wg2 = (const float*)d_in[9];
    const float* bg2 = (const float*)d_in[10];
    float* out = (float*)d_out;

    char* ws = (char*)d_ws;
    _Float16* xb  = (_Float16*)(ws);                         // 16 MB (frag)
    _Float16* W1F = (_Float16*)(ws + 16777216ull);           // 32 MB (frag)
    _Float16* W2F = (_Float16*)(ws + 50331648ull);           // 32 MB (frag)
    float*    f   = (float*)   (ws + 83886080ull);           // 0.5 MB
    char* hbase = ws + 84410368ull;

    int g = 1;
    const int cands[4] = {16, 8, 4, 2};
    for (int ci = 0; ci < 4; ++ci) {
        const size_t need = 84410368ull + 2ull * cands[ci] * 16777216ull;
        if (need <= ws_size) { g = cands[ci]; break; }
    }
    _Float16* h0 = (_Float16*)hbase;
    _Float16* h1 = (_Float16*)(hbase + (size_t)g * 16777216ull);

    castx_kernel<<<dim3(16, 128), 256, 0, stream>>>(x, xb);
    wtr_kernel<<<dim3(16, 16, 32), 256, 0, stream>>>(W1, W2, W1F, W2F);
    zerof_kernel<<<128, 256, 0, stream>>>(f);

    for (int e0 = 0; e0 < 16; e0 += g) {
        gemm_kernel<0><<<dim3(8, 16 * g), 512, 0, stream>>>(
            xb, W1F + (size_t)e0 * 1048576ull, b1 + (size_t)e0 * 1024, h0, 0,
            nullptr, nullptr, 0);
        gemm_kernel<1><<<dim3(8, 16 * g), 512, 0, stream>>>(
            h0, W2F + (size_t)e0 * 1048576ull, b2 + (size_t)e0 * 1024, h1, 8192ull * 1024ull,
            nullptr, nullptr, 0);
        gemm_kernel<2><<<dim3(8, 16 * g), 512, 0, stream>>>(
            h1, W2F + (size_t)e0 * 1048576ull, b2 + (size_t)e0 * 1024, h0, 8192ull * 1024ull,
            Wo, f, e0);
    }
    final_kernel<<<1024, 256, 0, stream>>>(x, Wg1, bg1, Wg2, bg2, f, bo, out);
}

// Round 6
// 862.292 us; speedup vs baseline: 6.5707x; 6.5707x over previous
//
#include <hip/hip_runtime.h>
#include <hip/hip_bf16.h>
#include <cstdint>
#include <cstddef>

// MultiGateMixExperts: fp16 MFMA GEMMs, frag-major layout.
// Frag-major layout: frag(tile16 t, kchunk32 c) = 1KB at ((t*32+c)*64+lane)*16B;
// lane l holds M[row=t*16+(l&15)][k=c*32+(l>>4)*8 .. +7] (fp16).
// R11 == R10 resubmit (R5 bench was an infra failure: container died before
// running; kernel re-audited for bounds/hang vectors — none).
// R10: ALGEBRAIC FOLD — stage 3 eliminated. Since Wo is a per-expert vector,
//   f = (relu(h_a)@W2 + b2)·Wo + bo = relu(h_a)·(W2@Wo) + (b2·Wo + bo)
// so precompute v[e] = W2[e]@Wo[e] (prep_kernel, ~11us) and fold the f-dot
// into stage 2's epilogue (which already has relu(h_a) in registers).
// 12 gemm dispatches -> 4 (g=8); h1 write+read traffic gone; h1 workspace
// freed -> g=8 fits. GEMM is the PROVEN R6 structure (128^2, 4 waves, 32KB
// LDS dbuf, 86us/35% MfmaUtil; R7-R9 schedule variants all <= this).
// h0 = sigmoid(x@W1[e]+b1)   [relu(h0)=h0 since sigmoid>0]
// f  = sum_n relu(h0@W2[e]+b2)[n] * v[e][n]  (atomicAdd over n-blocks)
// out_i = softmax(x@Wg_i+bg_i) . (f + bo2)

using half8   = __attribute__((ext_vector_type(8))) _Float16;
using floatx4 = __attribute__((ext_vector_type(4))) float;

// ---------------------------------------------------------------- GEMM ------
// ACT: 0=sigmoid (writes C in frag layout), 2=relu+f-dot fused (no C store).
// Block 128x128, 4 waves (2x2), wave tile 64x64 (4x4 of 16x16x32).
template<int ACT>
__global__ __launch_bounds__(256, 3)
void gemm_kernel(const _Float16* __restrict__ A, const _Float16* __restrict__ Bt,
                 const float* __restrict__ bias, _Float16* __restrict__ C,
                 size_t a_estride,
                 const float* __restrict__ Wo, float* __restrict__ f, int e0)
{
    // 2 x 16KB k-chunk buffers: frag f (0..7 = A m-tiles, 8..15 = B n-tiles),
    // 512 halves each, lane-linear. Reused as epilogue repack tile.
    __shared__ __align__(16) _Float16 sbuf[2][16 * 512];

    const int tid  = threadIdx.x;
    const int lane = tid & 63;
    const int w    = tid >> 6;      // wave 0..3
    const int wm   = w & 1;
    const int wn   = w >> 1;

    // --- XCD-aware windowed remap (gridDim = {8, 64, g}) ---
    const int g    = gridDim.z;
    const int flat = blockIdx.x + (blockIdx.y << 3) + (blockIdx.z << 9);
    const int xcd  = flat & 7;
    int s = flat >> 3;
    int le, mb_base;
    if (g <= 8) {
        const int p = 8 / g;            // XCDs per expert
        le = xcd / p;
        mb_base = (xcd % p) * (64 / p);
    } else {                            // g == 16
        le = (xcd << 1) | (s >> 9);
        s &= 511;
        mb_base = 0;
    }
    const int nb = (s >> 2) & 7;
    const int mb = mb_base + (s >> 5) * 4 + (s & 3);
    const int m0 = mb * 128;
    const int n0 = nb * 128;

    const _Float16* Ae = A   + (size_t)le * a_estride;
    const _Float16* Be = Bt  + (size_t)le * (1024ull * 1024ull);
    const float*    be = bias + (size_t)le * 1024ull;
    _Float16*       Ce = C   + (size_t)le * (8192ull * 1024ull);

    const int mtb_blk = m0 >> 4;          // block's first A m-tile (8 total)
    const int ntb_blk = n0 >> 4;          // block's first B n-tile (8 total)
    const int mtb = mtb_blk + wm * 4;     // wave's first m-tile

    // staging: wave w owns frags w*4 .. w*4+3; per-lane global src (+lane*16B),
    // advanced 512 halves per staged chunk.
    const _Float16* gs[4];
#pragma unroll
    for (int u = 0; u < 4; ++u) {
        const int fidx = w * 4 + u;
        gs[u] = (fidx < 8)
            ? (Ae + (size_t)(mtb_blk + fidx) * (32 * 512) + lane * 8)
            : (Be + (size_t)(ntb_blk + (fidx - 8)) * (32 * 512) + lane * 8);
    }

    floatx4 acc[4][4];
#pragma unroll
    for (int i = 0; i < 4; ++i)
#pragma unroll
        for (int j = 0; j < 4; ++j) { floatx4 z = {0.f, 0.f, 0.f, 0.f}; acc[i][j] = z; }

    auto STAGE = [&](_Float16* buf) {
#pragma unroll
        for (int u = 0; u < 4; ++u) {
            __builtin_amdgcn_global_load_lds(
                (const __attribute__((address_space(1))) void*)gs[u],
                (__attribute__((address_space(3))) void*)(buf + (w * 4 + u) * 512),
                16, 0, 0);
            gs[u] += 512;
        }
    };
    auto COMPUTE = [&](const _Float16* buf) {
        half8 a[4], b[4];
#pragma unroll
        for (int i = 0; i < 4; ++i)
            a[i] = *(const half8*)(buf + (wm * 4 + i) * 512 + lane * 8);
#pragma unroll
        for (int j = 0; j < 4; ++j)
            b[j] = *(const half8*)(buf + 4096 + (wn * 4 + j) * 512 + lane * 8);
#pragma unroll
        for (int i = 0; i < 4; ++i)
#pragma unroll
            for (int j = 0; j < 4; ++j)
                acc[i][j] = __builtin_amdgcn_mfma_f32_16x16x32_f16(a[i], b[j], acc[i][j], 0, 0, 0);
    };

    // K = 1024 -> 32 chunks of 32. Double-buffered, 1 barrier per chunk.
    STAGE(sbuf[0]);                       // chunk 0
    __syncthreads();
#pragma unroll 1
    for (int c = 0; c < 30; c += 2) {
        STAGE(sbuf[1]);                   // chunk c+1
        COMPUTE(sbuf[0]);                 // chunk c
        __syncthreads();
        STAGE(sbuf[0]);                   // chunk c+2
        COMPUTE(sbuf[1]);                 // chunk c+1
        __syncthreads();
    }
    STAGE(sbuf[1]);                       // chunk 31
    COMPUTE(sbuf[0]);                     // chunk 30
    __syncthreads();
    COMPUTE(sbuf[1]);                     // chunk 31

    // ----- epilogue; C/D layout: col=lane&15, row=(lane>>4)*4+r -----
    const int q   = lane >> 4;
    const int l15 = lane & 15;
    float bj[4];
#pragma unroll
    for (int j = 0; j < 4; ++j) bj[j] = be[n0 + wn * 64 + j * 16 + l15];

    if (ACT == 2) {
        // f[m, e0+le] += sum_n relu(acc + b2[n]) * v[e0+le, n]
        const float* we = Wo + (size_t)(e0 + le) * 1024;
        float wj[4];
#pragma unroll
        for (int j = 0; j < 4; ++j) wj[j] = we[n0 + wn * 64 + j * 16 + l15];
#pragma unroll
        for (int i = 0; i < 4; ++i) {
            const int mbase = m0 + wm * 64 + i * 16 + q * 4;
#pragma unroll
            for (int r = 0; r < 4; ++r) {
                float sacc = 0.f;
#pragma unroll
                for (int j = 0; j < 4; ++j)
                    sacc += fmaxf(acc[i][j][r] + bj[j], 0.0f) * wj[j];
#pragma unroll
                for (int m = 1; m < 16; m <<= 1) sacc += __shfl_xor(sacc, m, 64);
                if (l15 == 0) atomicAdd(&f[(size_t)(mbase + r) * 16 + (e0 + le)], sacc);
            }
        }
    } else {
        // per-wave LDS repack reusing the staging buffer (2 passes of 32 rows;
        // no cross-wave access after the barrier -> no further barriers)
        __syncthreads();                  // all waves done reading sbuf
        _Float16* T = &sbuf[0][0] + w * (32 * 72);
        const int kcg0 = ((n0 + wn * 64) >> 5);
#pragma unroll
        for (int p = 0; p < 2; ++p) {
#pragma unroll
            for (int i2 = 0; i2 < 2; ++i2) {
                const int i = p * 2 + i2;
#pragma unroll
                for (int r = 0; r < 4; ++r) {
                    const int row = i2 * 16 + q * 4 + r;
#pragma unroll
                    for (int j = 0; j < 4; ++j) {
                        float v = acc[i][j][r] + bj[j];
                        v = 1.0f / (1.0f + __expf(-v));   // ACT==0: sigmoid
                        T[row * 72 + j * 16 + l15] = (_Float16)v;
                    }
                }
            }
#pragma unroll
            for (int i2 = 0; i2 < 2; ++i2) {
                const int i = p * 2 + i2;
                const int mt = mtb + i;
#pragma unroll
                for (int kci = 0; kci < 2; ++kci) {
                    half8 v = *(const half8*)(T + (i2 * 16 + l15) * 72 + kci * 32 + q * 8);
                    *(half8*)(Ce + ((size_t)mt * 32 + kcg0 + kci) * 512 + lane * 8) = v;
                }
            }
        }
    }
}

// --------------------------------------- cast x to fp16 frag layout ---------
__global__ __launch_bounds__(256)
void castx_kernel(const float* __restrict__ x, _Float16* __restrict__ xb)
{
    __shared__ _Float16 tile[64 * 72];   // [m-local][k-local]
    const int k0 = blockIdx.x * 64;
    const int m0 = blockIdx.y * 64;
    const int tid = threadIdx.x;
    const int col4 = (tid & 15) * 4;
    const int rb   = tid >> 4;           // 0..15
#pragma unroll
    for (int p = 0; p < 4; ++p) {
        const int row = rb + p * 16;
        float4 a = *(const float4*)(x + (size_t)(m0 + row) * 1024 + k0 + col4);
        _Float16* d = tile + row * 72 + col4;
        d[0] = (_Float16)a.x; d[1] = (_Float16)a.y; d[2] = (_Float16)a.z; d[3] = (_Float16)a.w;
    }
    __syncthreads();
    const int lane = tid & 63, w = tid >> 6;
    const int l15 = lane & 15, q = lane >> 4;
#pragma unroll
    for (int ff = 0; ff < 2; ++ff) {
        const int fidx = w * 2 + ff;
        const int mi = fidx >> 1, kci = fidx & 1;
        half8 v = *(const half8*)(tile + (mi * 16 + l15) * 72 + kci * 32 + q * 8);
        const size_t mt = (m0 >> 4) + mi, kc = (k0 >> 5) + kci;
        *(half8*)(xb + (mt * 32 + kc) * 512 + lane * 8) = v;
    }
}

// ------------------- W1/W2 [d][h] fp32 -> frag-major fp16 (n=h, k=d) --------
__global__ __launch_bounds__(256)
void wtr_kernel(const float* __restrict__ W1, const float* __restrict__ W2,
                _Float16* __restrict__ W1F, _Float16* __restrict__ W2F)
{
    __shared__ _Float16 tile[64 * 73];   // [k-local][n-local], pad 73
    const int z = blockIdx.z;
    const float* src = (z < 16) ? (W1 + (size_t)z * 1048576ull) : (W2 + (size_t)(z - 16) * 1048576ull);
    _Float16*    dst = (z < 16) ? (W1F + (size_t)z * 1048576ull) : (W2F + (size_t)(z - 16) * 1048576ull);
    const int n0 = blockIdx.x * 64;
    const int k0 = blockIdx.y * 64;
    const int tid = threadIdx.x;
    const int col = tid & 63;
    const int rb  = tid >> 6;            // 0..3
#pragma unroll
    for (int p = 0; p < 16; ++p) {
        const int row = rb * 16 + p;
        tile[row * 73 + col] = (_Float16)src[(size_t)(k0 + row) * 1024 + n0 + col];
    }
    __syncthreads();
    const int lane = tid & 63, w = tid >> 6;
    const int l15 = lane & 15, q = lane >> 4;
#pragma unroll
    for (int ff = 0; ff < 2; ++ff) {
        const int fidx = w * 2 + ff;
        const int nti = fidx >> 1, kci = fidx & 1;
        half8 v;
#pragma unroll
        for (int jj = 0; jj < 8; ++jj)
            v[jj] = tile[(kci * 32 + q * 8 + jj) * 73 + nti * 16 + l15];
        const size_t nt = (n0 >> 4) + nti, kc = (k0 >> 5) + kci;
        *(half8*)(dst + (nt * 32 + kc) * 512 + lane * 8) = v;
    }
}

// ---------------------------------------------------- zero f ----------------
__global__ __launch_bounds__(256)
void zerof_kernel(float* __restrict__ f)
{
    const size_t i = ((size_t)blockIdx.x * 256 + threadIdx.x) * 4;
    float4 z = {0.f, 0.f, 0.f, 0.f};
    *(float4*)(f + i) = z;
}

// --------- prep: v[e] = W2[e] @ Wo[e]  (fp32), bo2[e] = b2[e].Wo[e] + bo[e] --
// one wave per output element; coalesced row reads + shuffle reduce.
__global__ __launch_bounds__(256)
void prep_kernel(const float* __restrict__ W2, const float* __restrict__ Wo,
                 const float* __restrict__ b2, const float* __restrict__ bo,
                 float* __restrict__ v, float* __restrict__ bo2)
{
    const int lane = threadIdx.x & 63;
    const int wv   = threadIdx.x >> 6;
    const int r    = blockIdx.x * 4 + wv;
    if (r < 16384) {
        const int e = r >> 10, h = r & 1023;
        const float* row = W2 + ((size_t)e << 20) + ((size_t)h << 10);
        const float* wo  = Wo + ((size_t)e << 10);
        float s = 0.f;
#pragma unroll
        for (int t = 0; t < 16; ++t) s += row[t * 64 + lane] * wo[t * 64 + lane];
#pragma unroll
        for (int m = 1; m < 64; m <<= 1) s += __shfl_xor(s, m, 64);
        if (lane == 0) v[((size_t)e << 10) + h] = s;
    } else if (r < 16400) {
        const int e = r - 16384;
        const float* br = b2 + ((size_t)e << 10);
        const float* wo = Wo + ((size_t)e << 10);
        float s = 0.f;
#pragma unroll
        for (int t = 0; t < 16; ++t) s += br[t * 64 + lane] * wo[t * 64 + lane];
#pragma unroll
        for (int m = 1; m < 64; m <<= 1) s += __shfl_xor(s, m, 64);
        if (lane == 0) bo2[e] = s + bo[e];
    }
}

// ------------------ gates (fp32, full precision) + softmax + combine --------
__global__ __launch_bounds__(256)
void final_kernel(const float* __restrict__ x,
                  const float* __restrict__ Wg1, const float* __restrict__ bg1,
                  const float* __restrict__ Wg2, const float* __restrict__ bg2,
                  const float* __restrict__ f, const float* __restrict__ bo2,
                  float* __restrict__ out)
{
    const int lane = threadIdx.x & 63;
    const int w    = threadIdx.x >> 6;
    const int b    = blockIdx.x * 8 + w * 2;
    const float* xA = x + (size_t)b * 1024;
    const float* xB = xA + 1024;
    float g1A[16], g2A[16], g1B[16], g2B[16];
#pragma unroll
    for (int e = 0; e < 16; ++e) { g1A[e] = 0.f; g2A[e] = 0.f; g1B[e] = 0.f; g2B[e] = 0.f; }
#pragma unroll 2
    for (int t = 0; t < 16; ++t) {
        const int d = t * 64 + lane;
        const float xa = xA[d];
        const float xb2 = xB[d];
        const float4* w1 = (const float4*)(Wg1 + (size_t)d * 16);
        const float4* w2 = (const float4*)(Wg2 + (size_t)d * 16);
#pragma unroll
        for (int q4 = 0; q4 < 4; ++q4) {
            const float4 c1 = w1[q4];
            const float4 c2 = w2[q4];
#pragma unroll
            for (int c = 0; c < 4; ++c) {
                const int e = q4 * 4 + c;
                const float v1 = (c == 0) ? c1.x : (c == 1) ? c1.y : (c == 2) ? c1.z : c1.w;
                const float v2 = (c == 0) ? c2.x : (c == 1) ? c2.y : (c == 2) ? c2.z : c2.w;
                g1A[e] += xa * v1; g1B[e] += xb2 * v1;
                g2A[e] += xa * v2; g2B[e] += xb2 * v2;
            }
        }
    }
#pragma unroll
    for (int e = 0; e < 16; ++e) {
#pragma unroll
        for (int m = 1; m < 64; m <<= 1) {
            g1A[e] += __shfl_xor(g1A[e], m, 64);
            g2A[e] += __shfl_xor(g2A[e], m, 64);
            g1B[e] += __shfl_xor(g1B[e], m, 64);
            g2B[e] += __shfl_xor(g2B[e], m, 64);
        }
    }
    const float* fbA = f + (size_t)b * 16;
    const float* fbB = fbA + 16;
#pragma unroll
    for (int rr = 0; rr < 2; ++rr) {
        const float* gp1 = rr ? g1B : g1A;
        const float* gp2 = rr ? g2B : g2A;
        const float* fb  = rr ? fbB : fbA;
        float a1[16], a2[16], m1 = -1e30f, m2 = -1e30f;
#pragma unroll
        for (int e = 0; e < 16; ++e) {
            a1[e] = gp1[e] + bg1[e]; m1 = fmaxf(m1, a1[e]);
            a2[e] = gp2[e] + bg2[e]; m2 = fmaxf(m2, a2[e]);
        }
        float s1 = 0.f, s2 = 0.f, o1 = 0.f, o2 = 0.f;
#pragma unroll
        for (int e = 0; e < 16; ++e) {
            a1[e] = __expf(a1[e] - m1); s1 += a1[e];
            a2[e] = __expf(a2[e] - m2); s2 += a2[e];
        }
#pragma unroll
        for (int e = 0; e < 16; ++e) {
            const float fe = fb[e] + bo2[e];
            o1 += a1[e] * fe; o2 += a2[e] * fe;
        }
        if (lane == 0) { out[b + rr] = o1 / s1; out[8192 + b + rr] = o2 / s2; }
    }
}

// ----------------------------------------------------------------------------
extern "C" void kernel_launch(void* const* d_in, const int* in_sizes, int n_in,
                              void* d_out, int out_size, void* d_ws, size_t ws_size,
                              hipStream_t stream)
{
    const float* x   = (const float*)d_in[0];
    const float* W1  = (const float*)d_in[1];
    const float* b1  = (const float*)d_in[2];
    const float* W2  = (const float*)d_in[3];
    const float* b2  = (const float*)d_in[4];
    const float* Wo  = (const float*)d_in[5];
    const float* bo  = (const float*)d_in[6];
    const float* Wg1 = (const float*)d_in[7];
    const float* bg1 = (const float*)d_in[8];
    const float* Wg2 = (const float*)d_in[9];
    const float* bg2 = (const float*)d_in[10];
    float* out = (float*)d_out;

    char* ws = (char*)d_ws;
    _Float16* xb  = (_Float16*)(ws);                         // 16 MB (frag)
    _Float16* W1F = (_Float16*)(ws + 16777216ull);           // 32 MB (frag)
    _Float16* W2F = (_Float16*)(ws + 50331648ull);           // 32 MB (frag)
    float*    f   = (float*)   (ws + 83886080ull);           // 0.5 MB
    float*    v   = (float*)   (ws + 84410368ull);           // 64 KB
    float*    bo2 = (float*)   (ws + 84475904ull);           // 64 B
    char* hbase = ws + 84475968ull;

    int g = 1;
    const int cands[4] = {16, 8, 4, 2};
    for (int ci = 0; ci < 4; ++ci) {
        const size_t need = 84475968ull + (size_t)cands[ci] * 16777216ull;
        if (need <= ws_size) { g = cands[ci]; break; }
    }
    _Float16* h0 = (_Float16*)hbase;

    castx_kernel<<<dim3(16, 128), 256, 0, stream>>>(x, xb);
    wtr_kernel<<<dim3(16, 16, 32), 256, 0, stream>>>(W1, W2, W1F, W2F);
    zerof_kernel<<<128, 256, 0, stream>>>(f);
    prep_kernel<<<4100, 256, 0, stream>>>(W2, Wo, b2, bo, v, bo2);

    for (int e0 = 0; e0 < 16; e0 += g) {
        gemm_kernel<0><<<dim3(8, 64, g), 256, 0, stream>>>(
            xb, W1F + (size_t)e0 * 1048576ull, b1 + (size_t)e0 * 1024, h0, 0,
            nullptr, nullptr, 0);
        gemm_kernel<2><<<dim3(8, 64, g), 256, 0, stream>>>(
            h0, W2F + (size_t)e0 * 1048576ull, b2 + (size_t)e0 * 1024, h0, 8192ull * 1024ull,
            v, f, e0);
    }
    final_kernel<<<1024, 256, 0, stream>>>(x, Wg1, bg1, Wg2, bg2, f, bo2, out);
}

// Round 7
// 838.511 us; speedup vs baseline: 6.7571x; 1.0284x over previous
//
#include <hip/hip_runtime.h>
#include <hip/hip_bf16.h>
#include <cstdint>
#include <cstddef>

// MultiGateMixExperts: fp16 MFMA GEMMs, frag-major layout.
// Frag-major layout: frag(tile16 t, kchunk32 c) = 1KB at ((t*32+c)*64+lane)*16B;
// lane l holds M[row=t*16+(l&15)][k=c*32+(l>>4)*8 .. +7] (fp16).
// R12: aux consolidation on top of R10/R11's fold (1103->862us, matched):
//  - wtr: float4 loads (was 256B/wave scalar reads of 128MB fp32 -> full 1KB)
//  - v = W2@Wo folded into wtr's W2 pass using the fp32 registers (4 FMA +
//    4-lane shuffle + atomicAdd per row; v zeroed by extended zerof) ->
//    prep_kernel's 64MB W2 re-read eliminated; only a 16-wave prep_bo2 left.
//  - GEMM untouched: proven R6 structure (128^2, 4 waves, 32KB LDS dbuf,
//    ~178us/8experts = 768 TF, MfmaUtil 35% — the m97-structure ceiling at
//    K=1024; R7-R9 alternatives all regressed).
// h0 = sigmoid(x@W1[e]+b1)   [relu(h0)=h0 since sigmoid>0]
// f  = sum_n relu(h0@W2[e]+b2)[n] * v[e][n]  (atomicAdd over n-blocks)
// out_i = softmax(x@Wg_i+bg_i) . (f + bo2),  bo2 = b2.Wo + bo

using half8   = __attribute__((ext_vector_type(8))) _Float16;
using floatx4 = __attribute__((ext_vector_type(4))) float;

// ---------------------------------------------------------------- GEMM ------
// ACT: 0=sigmoid (writes C in frag layout), 2=relu+f-dot fused (no C store).
// Block 128x128, 4 waves (2x2), wave tile 64x64 (4x4 of 16x16x32).
template<int ACT>
__global__ __launch_bounds__(256, 3)
void gemm_kernel(const _Float16* __restrict__ A, const _Float16* __restrict__ Bt,
                 const float* __restrict__ bias, _Float16* __restrict__ C,
                 size_t a_estride,
                 const float* __restrict__ Wo, float* __restrict__ f, int e0)
{
    // 2 x 16KB k-chunk buffers: frag f (0..7 = A m-tiles, 8..15 = B n-tiles),
    // 512 halves each, lane-linear. Reused as epilogue repack tile.
    __shared__ __align__(16) _Float16 sbuf[2][16 * 512];

    const int tid  = threadIdx.x;
    const int lane = tid & 63;
    const int w    = tid >> 6;      // wave 0..3
    const int wm   = w & 1;
    const int wn   = w >> 1;

    // --- XCD-aware windowed remap (gridDim = {8, 64, g}) ---
    const int g    = gridDim.z;
    const int flat = blockIdx.x + (blockIdx.y << 3) + (blockIdx.z << 9);
    const int xcd  = flat & 7;
    int s = flat >> 3;
    int le, mb_base;
    if (g <= 8) {
        const int p = 8 / g;            // XCDs per expert
        le = xcd / p;
        mb_base = (xcd % p) * (64 / p);
    } else {                            // g == 16
        le = (xcd << 1) | (s >> 9);
        s &= 511;
        mb_base = 0;
    }
    const int nb = (s >> 2) & 7;
    const int mb = mb_base + (s >> 5) * 4 + (s & 3);
    const int m0 = mb * 128;
    const int n0 = nb * 128;

    const _Float16* Ae = A   + (size_t)le * a_estride;
    const _Float16* Be = Bt  + (size_t)le * (1024ull * 1024ull);
    const float*    be = bias + (size_t)le * 1024ull;
    _Float16*       Ce = C   + (size_t)le * (8192ull * 1024ull);

    const int mtb_blk = m0 >> 4;          // block's first A m-tile (8 total)
    const int ntb_blk = n0 >> 4;          // block's first B n-tile (8 total)
    const int mtb = mtb_blk + wm * 4;     // wave's first m-tile

    // staging: wave w owns frags w*4 .. w*4+3; per-lane global src (+lane*16B),
    // advanced 512 halves per staged chunk.
    const _Float16* gs[4];
#pragma unroll
    for (int u = 0; u < 4; ++u) {
        const int fidx = w * 4 + u;
        gs[u] = (fidx < 8)
            ? (Ae + (size_t)(mtb_blk + fidx) * (32 * 512) + lane * 8)
            : (Be + (size_t)(ntb_blk + (fidx - 8)) * (32 * 512) + lane * 8);
    }

    floatx4 acc[4][4];
#pragma unroll
    for (int i = 0; i < 4; ++i)
#pragma unroll
        for (int j = 0; j < 4; ++j) { floatx4 z = {0.f, 0.f, 0.f, 0.f}; acc[i][j] = z; }

    auto STAGE = [&](_Float16* buf) {
#pragma unroll
        for (int u = 0; u < 4; ++u) {
            __builtin_amdgcn_global_load_lds(
                (const __attribute__((address_space(1))) void*)gs[u],
                (__attribute__((address_space(3))) void*)(buf + (w * 4 + u) * 512),
                16, 0, 0);
            gs[u] += 512;
        }
    };
    auto COMPUTE = [&](const _Float16* buf) {
        half8 a[4], b[4];
#pragma unroll
        for (int i = 0; i < 4; ++i)
            a[i] = *(const half8*)(buf + (wm * 4 + i) * 512 + lane * 8);
#pragma unroll
        for (int j = 0; j < 4; ++j)
            b[j] = *(const half8*)(buf + 4096 + (wn * 4 + j) * 512 + lane * 8);
#pragma unroll
        for (int i = 0; i < 4; ++i)
#pragma unroll
            for (int j = 0; j < 4; ++j)
                acc[i][j] = __builtin_amdgcn_mfma_f32_16x16x32_f16(a[i], b[j], acc[i][j], 0, 0, 0);
    };

    // K = 1024 -> 32 chunks of 32. Double-buffered, 1 barrier per chunk.
    STAGE(sbuf[0]);                       // chunk 0
    __syncthreads();
#pragma unroll 1
    for (int c = 0; c < 30; c += 2) {
        STAGE(sbuf[1]);                   // chunk c+1
        COMPUTE(sbuf[0]);                 // chunk c
        __syncthreads();
        STAGE(sbuf[0]);                   // chunk c+2
        COMPUTE(sbuf[1]);                 // chunk c+1
        __syncthreads();
    }
    STAGE(sbuf[1]);                       // chunk 31
    COMPUTE(sbuf[0]);                     // chunk 30
    __syncthreads();
    COMPUTE(sbuf[1]);                     // chunk 31

    // ----- epilogue; C/D layout: col=lane&15, row=(lane>>4)*4+r -----
    const int q   = lane >> 4;
    const int l15 = lane & 15;
    float bj[4];
#pragma unroll
    for (int j = 0; j < 4; ++j) bj[j] = be[n0 + wn * 64 + j * 16 + l15];

    if (ACT == 2) {
        // f[m, e0+le] += sum_n relu(acc + b2[n]) * v[e0+le, n]
        const float* we = Wo + (size_t)(e0 + le) * 1024;
        float wj[4];
#pragma unroll
        for (int j = 0; j < 4; ++j) wj[j] = we[n0 + wn * 64 + j * 16 + l15];
#pragma unroll
        for (int i = 0; i < 4; ++i) {
            const int mbase = m0 + wm * 64 + i * 16 + q * 4;
#pragma unroll
            for (int r = 0; r < 4; ++r) {
                float sacc = 0.f;
#pragma unroll
                for (int j = 0; j < 4; ++j)
                    sacc += fmaxf(acc[i][j][r] + bj[j], 0.0f) * wj[j];
#pragma unroll
                for (int m = 1; m < 16; m <<= 1) sacc += __shfl_xor(sacc, m, 64);
                if (l15 == 0) atomicAdd(&f[(size_t)(mbase + r) * 16 + (e0 + le)], sacc);
            }
        }
    } else {
        // per-wave LDS repack reusing the staging buffer (2 passes of 32 rows;
        // no cross-wave access after the barrier -> no further barriers)
        __syncthreads();                  // all waves done reading sbuf
        _Float16* T = &sbuf[0][0] + w * (32 * 72);
        const int kcg0 = ((n0 + wn * 64) >> 5);
#pragma unroll
        for (int p = 0; p < 2; ++p) {
#pragma unroll
            for (int i2 = 0; i2 < 2; ++i2) {
                const int i = p * 2 + i2;
#pragma unroll
                for (int r = 0; r < 4; ++r) {
                    const int row = i2 * 16 + q * 4 + r;
#pragma unroll
                    for (int j = 0; j < 4; ++j) {
                        float v = acc[i][j][r] + bj[j];
                        v = 1.0f / (1.0f + __expf(-v));   // ACT==0: sigmoid
                        T[row * 72 + j * 16 + l15] = (_Float16)v;
                    }
                }
            }
#pragma unroll
            for (int i2 = 0; i2 < 2; ++i2) {
                const int i = p * 2 + i2;
                const int mt = mtb + i;
#pragma unroll
                for (int kci = 0; kci < 2; ++kci) {
                    half8 v = *(const half8*)(T + (i2 * 16 + l15) * 72 + kci * 32 + q * 8);
                    *(half8*)(Ce + ((size_t)mt * 32 + kcg0 + kci) * 512 + lane * 8) = v;
                }
            }
        }
    }
}

// --------------------------------------- cast x to fp16 frag layout ---------
__global__ __launch_bounds__(256)
void castx_kernel(const float* __restrict__ x, _Float16* __restrict__ xb)
{
    __shared__ _Float16 tile[64 * 72];   // [m-local][k-local]
    const int k0 = blockIdx.x * 64;
    const int m0 = blockIdx.y * 64;
    const int tid = threadIdx.x;
    const int col4 = (tid & 15) * 4;
    const int rb   = tid >> 4;           // 0..15
#pragma unroll
    for (int p = 0; p < 4; ++p) {
        const int row = rb + p * 16;
        float4 a = *(const float4*)(x + (size_t)(m0 + row) * 1024 + k0 + col4);
        _Float16* d = tile + row * 72 + col4;
        d[0] = (_Float16)a.x; d[1] = (_Float16)a.y; d[2] = (_Float16)a.z; d[3] = (_Float16)a.w;
    }
    __syncthreads();
    const int lane = tid & 63, w = tid >> 6;
    const int l15 = lane & 15, q = lane >> 4;
#pragma unroll
    for (int ff = 0; ff < 2; ++ff) {
        const int fidx = w * 2 + ff;
        const int mi = fidx >> 1, kci = fidx & 1;
        half8 v = *(const half8*)(tile + (mi * 16 + l15) * 72 + kci * 32 + q * 8);
        const size_t mt = (m0 >> 4) + mi, kc = (k0 >> 5) + kci;
        *(half8*)(xb + (mt * 32 + kc) * 512 + lane * 8) = v;
    }
}

// ------------- W1/W2 [d][h] fp32 -> frag-major fp16 (n=h, k=d) --------------
// R12: float4 loads; for W2 tiles additionally fold the v = W2@Wo partial dot
// using the fp32 registers (full precision), atomicAdd into v (zeroed by
// zerof). Rows here are the k-dim (= h_in of v), cols the n-dim (h_out).
__global__ __launch_bounds__(256)
void wtr_kernel(const float* __restrict__ W1, const float* __restrict__ W2,
                _Float16* __restrict__ W1F, _Float16* __restrict__ W2F,
                const float* __restrict__ Wo, float* __restrict__ v)
{
    __shared__ _Float16 tile[64 * 73];   // [k-local][n-local], pad 73
    const int z = blockIdx.z;
    const float* src = (z < 16) ? (W1 + (size_t)z * 1048576ull) : (W2 + (size_t)(z - 16) * 1048576ull);
    _Float16*    dst = (z < 16) ? (W1F + (size_t)z * 1048576ull) : (W2F + (size_t)(z - 16) * 1048576ull);
    const int n0 = blockIdx.x * 64;
    const int k0 = blockIdx.y * 64;
    const int tid = threadIdx.x;
    const int lane = tid & 63, w = tid >> 6;
    const int l15 = lane & 15, q = lane >> 4;

    // vectorized load: 4 x float4 per thread (rows w*4+q+p*16, cols l15*4..+3)
    const int col4 = l15 * 4;
    const int rbase = w * 4 + q;
    float4 a4[4];
#pragma unroll
    for (int p = 0; p < 4; ++p) {
        const int row = rbase + p * 16;
        a4[p] = *(const float4*)(src + (size_t)(k0 + row) * 1024 + n0 + col4);
        _Float16* d = tile + row * 73 + col4;
        d[0] = (_Float16)a4[p].x; d[1] = (_Float16)a4[p].y;
        d[2] = (_Float16)a4[p].z; d[3] = (_Float16)a4[p].w;
    }

    if (z >= 16) {
        // v[e][k0+row] += sum_{n-slice} W2[e][k0+row][n0+c] * Wo[e][n0+c]
        const int e = z - 16;
        const float* wo = Wo + ((size_t)e << 10) + n0;
        float* ve = v + ((size_t)e << 10) + k0;
#pragma unroll
        for (int p = 0; p < 4; ++p) {
            float s = a4[p].x * wo[col4] + a4[p].y * wo[col4 + 1]
                    + a4[p].z * wo[col4 + 2] + a4[p].w * wo[col4 + 3];
            // reduce across the 16 lanes (same q) holding this row's 64 cols
            s += __shfl_xor(s, 1, 64);
            s += __shfl_xor(s, 2, 64);
            s += __shfl_xor(s, 4, 64);
            s += __shfl_xor(s, 8, 64);
            if (l15 == 0) atomicAdd(&ve[rbase + p * 16], s);
        }
    }

    __syncthreads();
#pragma unroll
    for (int ff = 0; ff < 2; ++ff) {
        const int fidx = w * 2 + ff;
        const int nti = fidx >> 1, kci = fidx & 1;
        half8 hv;
#pragma unroll
        for (int jj = 0; jj < 8; ++jj)
            hv[jj] = tile[(kci * 32 + q * 8 + jj) * 73 + nti * 16 + l15];
        const size_t nt = (n0 >> 4) + nti, kc = (k0 >> 5) + kci;
        *(half8*)(dst + (nt * 32 + kc) * 512 + lane * 8) = hv;
    }
}

// --------------------------- zero f (0.5MB) + v (64KB), contiguous ----------
__global__ __launch_bounds__(256)
void zerof_kernel(float* __restrict__ f)
{
    const size_t i = ((size_t)blockIdx.x * 256 + threadIdx.x) * 4;
    float4 z = {0.f, 0.f, 0.f, 0.f};
    *(float4*)(f + i) = z;
}

// ----------------- bo2[e] = b2[e].Wo[e] + bo[e]  (16 waves) -----------------
__global__ __launch_bounds__(64)
void prep_bo2_kernel(const float* __restrict__ b2, const float* __restrict__ Wo,
                     const float* __restrict__ bo, float* __restrict__ bo2)
{
    const int e = blockIdx.x;
    const int lane = threadIdx.x;
    const float* br = b2 + ((size_t)e << 10);
    const float* wo = Wo + ((size_t)e << 10);
    float s = 0.f;
#pragma unroll
    for (int t = 0; t < 16; ++t) s += br[t * 64 + lane] * wo[t * 64 + lane];
#pragma unroll
    for (int m = 1; m < 64; m <<= 1) s += __shfl_xor(s, m, 64);
    if (lane == 0) bo2[e] = s + bo[e];
}

// ------------------ gates (fp32, full precision) + softmax + combine --------
__global__ __launch_bounds__(256)
void final_kernel(const float* __restrict__ x,
                  const float* __restrict__ Wg1, const float* __restrict__ bg1,
                  const float* __restrict__ Wg2, const float* __restrict__ bg2,
                  const float* __restrict__ f, const float* __restrict__ bo2,
                  float* __restrict__ out)
{
    const int lane = threadIdx.x & 63;
    const int w    = threadIdx.x >> 6;
    const int b    = blockIdx.x * 8 + w * 2;
    const float* xA = x + (size_t)b * 1024;
    const float* xB = xA + 1024;
    float g1A[16], g2A[16], g1B[16], g2B[16];
#pragma unroll
    for (int e = 0; e < 16; ++e) { g1A[e] = 0.f; g2A[e] = 0.f; g1B[e] = 0.f; g2B[e] = 0.f; }
#pragma unroll 2
    for (int t = 0; t < 16; ++t) {
        const int d = t * 64 + lane;
        const float xa = xA[d];
        const float xb2 = xB[d];
        const float4* w1 = (const float4*)(Wg1 + (size_t)d * 16);
        const float4* w2 = (const float4*)(Wg2 + (size_t)d * 16);
#pragma unroll
        for (int q4 = 0; q4 < 4; ++q4) {
            const float4 c1 = w1[q4];
            const float4 c2 = w2[q4];
#pragma unroll
            for (int c = 0; c < 4; ++c) {
                const int e = q4 * 4 + c;
                const float v1 = (c == 0) ? c1.x : (c == 1) ? c1.y : (c == 2) ? c1.z : c1.w;
                const float v2 = (c == 0) ? c2.x : (c == 1) ? c2.y : (c == 2) ? c2.z : c2.w;
                g1A[e] += xa * v1; g1B[e] += xb2 * v1;
                g2A[e] += xa * v2; g2B[e] += xb2 * v2;
            }
        }
    }
#pragma unroll
    for (int e = 0; e < 16; ++e) {
#pragma unroll
        for (int m = 1; m < 64; m <<= 1) {
            g1A[e] += __shfl_xor(g1A[e], m, 64);
            g2A[e] += __shfl_xor(g2A[e], m, 64);
            g1B[e] += __shfl_xor(g1B[e], m, 64);
            g2B[e] += __shfl_xor(g2B[e], m, 64);
        }
    }
    const float* fbA = f + (size_t)b * 16;
    const float* fbB = fbA + 16;
#pragma unroll
    for (int rr = 0; rr < 2; ++rr) {
        const float* gp1 = rr ? g1B : g1A;
        const float* gp2 = rr ? g2B : g2A;
        const float* fb  = rr ? fbB : fbA;
        float a1[16], a2[16], m1 = -1e30f, m2 = -1e30f;
#pragma unroll
        for (int e = 0; e < 16; ++e) {
            a1[e] = gp1[e] + bg1[e]; m1 = fmaxf(m1, a1[e]);
            a2[e] = gp2[e] + bg2[e]; m2 = fmaxf(m2, a2[e]);
        }
        float s1 = 0.f, s2 = 0.f, o1 = 0.f, o2 = 0.f;
#pragma unroll
        for (int e = 0; e < 16; ++e) {
            a1[e] = __expf(a1[e] - m1); s1 += a1[e];
            a2[e] = __expf(a2[e] - m2); s2 += a2[e];
        }
#pragma unroll
        for (int e = 0; e < 16; ++e) {
            const float fe = fb[e] + bo2[e];
            o1 += a1[e] * fe; o2 += a2[e] * fe;
        }
        if (lane == 0) { out[b + rr] = o1 / s1; out[8192 + b + rr] = o2 / s2; }
    }
}

// ----------------------------------------------------------------------------
extern "C" void kernel_launch(void* const* d_in, const int* in_sizes, int n_in,
                              void* d_out, int out_size, void* d_ws, size_t ws_size,
                              hipStream_t stream)
{
    const float* x   = (const float*)d_in[0];
    const float* W1  = (const float*)d_in[1];
    const float* b1  = (const float*)d_in[2];
    const float* W2  = (const float*)d_in[3];
    const float* b2  = (const float*)d_in[4];
    const float* Wo  = (const float*)d_in[5];
    const float* bo  = (const float*)d_in[6];
    const float* Wg1 = (const float*)d_in[7];
    const float* bg1 = (const float*)d_in[8];
    const float* Wg2 = (const float*)d_in[9];
    const float* bg2 = (const float*)d_in[10];
    float* out = (float*)d_out;

    char* ws = (char*)d_ws;
    _Float16* xb  = (_Float16*)(ws);                         // 16 MB (frag)
    _Float16* W1F = (_Float16*)(ws + 16777216ull);           // 32 MB (frag)
    _Float16* W2F = (_Float16*)(ws + 50331648ull);           // 32 MB (frag)
    float*    f   = (float*)   (ws + 83886080ull);           // 0.5 MB
    float*    v   = (float*)   (ws + 84410368ull);           // 64 KB (after f)
    float*    bo2 = (float*)   (ws + 84475904ull);           // 64 B
    char* hbase = ws + 84475968ull;

    int g = 1;
    const int cands[4] = {16, 8, 4, 2};
    for (int ci = 0; ci < 4; ++ci) {
        const size_t need = 84475968ull + (size_t)cands[ci] * 16777216ull;
        if (need <= ws_size) { g = cands[ci]; break; }
    }
    _Float16* h0 = (_Float16*)hbase;

    // zerof covers f (131072 floats) + v (16384 floats), contiguous: 144 blocks
    zerof_kernel<<<144, 256, 0, stream>>>(f);
    castx_kernel<<<dim3(16, 128), 256, 0, stream>>>(x, xb);
    wtr_kernel<<<dim3(16, 16, 32), 256, 0, stream>>>(W1, W2, W1F, W2F, Wo, v);
    prep_bo2_kernel<<<16, 64, 0, stream>>>(b2, Wo, bo, bo2);

    for (int e0 = 0; e0 < 16; e0 += g) {
        gemm_kernel<0><<<dim3(8, 64, g), 256, 0, stream>>>(
            xb, W1F + (size_t)e0 * 1048576ull, b1 + (size_t)e0 * 1024, h0, 0,
            nullptr, nullptr, 0);
        gemm_kernel<2><<<dim3(8, 64, g), 256, 0, stream>>>(
            h0, W2F + (size_t)e0 * 1048576ull, b2 + (size_t)e0 * 1024, h0, 8192ull * 1024ull,
            v, f, e0);
    }
    final_kernel<<<1024, 256, 0, stream>>>(x, Wg1, bg1, Wg2, bg2, f, bo2, out);
}

// Round 8
// 784.309 us; speedup vs baseline: 7.2240x; 1.0691x over previous
//
#include <hip/hip_runtime.h>
#include <hip/hip_bf16.h>
#include <cstdint>
#include <cstddef>

// MultiGateMixExperts: fp16 MFMA GEMMs, frag-major layout.
// Frag-major layout: frag(tile16 t, kchunk32 c) = 1KB at ((t*32+c)*64+lane)*16B;
// lane l holds M[row=t*16+(l&15)][k=c*32+(l>>4)*8 .. +7] (fp16).
// R13: LDS-traffic reduction. Ratio analysis: the R6 128^2 tile moves 48KB of
// LDS per 1.05 MFLOP chunk (21.8 FLOP/B) = 35.6 TB/s chip-wide = 68% of the
// ~52 TB/s ds_read_b128 ceiling while MfmaUtil is 35% -> LDS pipe is the
// binding resource (why all R7/R8 schedule surgery was null). Fix: wave tile
// 64x128 (a[4] x b[8] -> 32 MFMA per 12 ds_read_b128), block 128x256, 4 waves,
// launch_bounds(256,2) (acc 128 + operands ~50 + addr ~30 ~= 210 VGPR, fits
// 256 cap, 2 waves/SIMD, 2 blocks/CU at 48KB LDS). 29 FLOP/LDS-byte (+33%).
// Same MFMA shape, same frag layout, same R6 loop; acc K-order unchanged.
// R10 fold retained: f = relu(h_a)·(W2@Wo) + (b2·Wo + bo); v from wtr pass.
// h0 = sigmoid(x@W1[e]+b1); f = sum_n relu(h0@W2[e]+b2)[n]*v[e][n] (atomics)
// out_i = softmax(x@Wg_i+bg_i) . (f + bo2)

using half8   = __attribute__((ext_vector_type(8))) _Float16;
using floatx4 = __attribute__((ext_vector_type(4))) float;

// ---------------------------------------------------------------- GEMM ------
// ACT: 0=sigmoid (writes C in frag layout), 2=relu+f-dot fused (no C store).
// Block 128x256, 4 waves (2m x 2n), wave tile 64x128 (4x8 of 16x16x32).
template<int ACT>
__global__ __launch_bounds__(256, 2)
void gemm_kernel(const _Float16* __restrict__ A, const _Float16* __restrict__ Bt,
                 const float* __restrict__ bias, _Float16* __restrict__ C,
                 size_t a_estride,
                 const float* __restrict__ Wo, float* __restrict__ f, int e0)
{
    // 2 x 24KB k-chunk buffers: frags 0..7 = A m-tiles, 8..23 = B n-tiles,
    // 512 halves each, lane-linear. Reused as epilogue repack tile.
    __shared__ __align__(16) _Float16 sbuf[2][24 * 512];

    const int tid  = threadIdx.x;
    const int lane = tid & 63;
    const int w    = tid >> 6;      // wave 0..3
    const int wm   = w & 1;         // m-half (64 rows)
    const int wn   = w >> 1;        // n-half (128 cols)

    // --- XCD-aware windowed remap (gridDim = {8, 32*g}) ---
    // per expert: 64 mb x 4 nb = 256 blocks. window = 4 mb x all 4 nb:
    // A-window 1MB + B 2MB ~ L2 per XCD.
    const int flat = blockIdx.x + (blockIdx.y << 3);
    const int xcd  = flat & 7;
    int s = flat >> 3;
    const int g = gridDim.y >> 5;
    int le, mb_base;
    if (g <= 8) {
        const int p = 8 / g;            // XCDs per expert
        le = xcd / p;
        mb_base = (xcd % p) * (64 / p);
    } else {                            // g == 16
        le = (xcd << 1) | (s >> 8);
        s &= 255;
        mb_base = 0;
    }
    const int nb = (s >> 2) & 3;
    const int mb = mb_base + (s >> 4) * 4 + (s & 3);
    const int m0 = mb * 128;
    const int n0 = nb * 256;

    const _Float16* Ae = A    + (size_t)le * a_estride;
    const _Float16* Be = Bt   + (size_t)le * (1024ull * 1024ull);
    const float*    be = bias + (size_t)le * 1024ull;
    _Float16*       Ce = C    + (size_t)le * (8192ull * 1024ull);

    const int mtb_blk = m0 >> 4;          // block's first A m-tile (8 total)
    const int ntb_blk = n0 >> 4;          // block's first B n-tile (16 total)

    // staging: wave w owns frags w*6 .. w*6+5 (24 total: 8 A + 16 B);
    // per-lane global src (+lane*16B), advanced 512 halves per staged chunk.
    const _Float16* gs[6];
#pragma unroll
    for (int u = 0; u < 6; ++u) {
        const int fidx = w * 6 + u;
        gs[u] = (fidx < 8)
            ? (Ae + (size_t)(mtb_blk + fidx) * (32 * 512) + lane * 8)
            : (Be + (size_t)(ntb_blk + (fidx - 8)) * (32 * 512) + lane * 8);
    }

    floatx4 acc[4][8];
#pragma unroll
    for (int i = 0; i < 4; ++i)
#pragma unroll
        for (int j = 0; j < 8; ++j) { floatx4 z = {0.f, 0.f, 0.f, 0.f}; acc[i][j] = z; }

    auto STAGE = [&](_Float16* buf) {
#pragma unroll
        for (int u = 0; u < 6; ++u) {
            __builtin_amdgcn_global_load_lds(
                (const __attribute__((address_space(1))) void*)gs[u],
                (__attribute__((address_space(3))) void*)(buf + (w * 6 + u) * 512),
                16, 0, 0);
            gs[u] += 512;
        }
    };
    auto COMPUTE = [&](const _Float16* buf) {
        half8 a[4], b[8];
#pragma unroll
        for (int i = 0; i < 4; ++i)
            a[i] = *(const half8*)(buf + (wm * 4 + i) * 512 + lane * 8);
#pragma unroll
        for (int j = 0; j < 8; ++j)
            b[j] = *(const half8*)(buf + 4096 + (wn * 8 + j) * 512 + lane * 8);
#pragma unroll
        for (int i = 0; i < 4; ++i)
#pragma unroll
            for (int j = 0; j < 8; ++j)
                acc[i][j] = __builtin_amdgcn_mfma_f32_16x16x32_f16(a[i], b[j], acc[i][j], 0, 0, 0);
    };

    // K = 1024 -> 32 chunks of 32. Double-buffered, 1 barrier per chunk.
    STAGE(sbuf[0]);                       // chunk 0
    __syncthreads();
#pragma unroll 1
    for (int c = 0; c < 30; c += 2) {
        STAGE(sbuf[1]);                   // chunk c+1
        COMPUTE(sbuf[0]);                 // chunk c
        __syncthreads();
        STAGE(sbuf[0]);                   // chunk c+2
        COMPUTE(sbuf[1]);                 // chunk c+1
        __syncthreads();
    }
    STAGE(sbuf[1]);                       // chunk 31
    COMPUTE(sbuf[0]);                     // chunk 30
    __syncthreads();
    COMPUTE(sbuf[1]);                     // chunk 31

    // ----- epilogue; C/D layout: col=lane&15, row=(lane>>4)*4+r -----
    const int q   = lane >> 4;
    const int l15 = lane & 15;
    float bj[8];
#pragma unroll
    for (int j = 0; j < 8; ++j) bj[j] = be[n0 + wn * 128 + j * 16 + l15];

    if (ACT == 2) {
        // f[m, e0+le] += sum_n relu(acc + b2[n]) * v[e0+le, n]
        const float* we = Wo + (size_t)(e0 + le) * 1024;
        float wj[8];
#pragma unroll
        for (int j = 0; j < 8; ++j) wj[j] = we[n0 + wn * 128 + j * 16 + l15];
#pragma unroll
        for (int i = 0; i < 4; ++i) {
            const int mbase = m0 + wm * 64 + i * 16 + q * 4;
#pragma unroll
            for (int r = 0; r < 4; ++r) {
                float sacc = 0.f;
#pragma unroll
                for (int j = 0; j < 8; ++j)
                    sacc += fmaxf(acc[i][j][r] + bj[j], 0.0f) * wj[j];
#pragma unroll
                for (int m = 1; m < 16; m <<= 1) sacc += __shfl_xor(sacc, m, 64);
                if (l15 == 0) atomicAdd(&f[(size_t)(mbase + r) * 16 + (e0 + le)], sacc);
            }
        }
    } else {
        // per-wave repack reusing sbuf[0] (private 3072-half region; same-wave
        // LDS RAW tracked by compiler, no barrier inside). One m-tile (16 rows
        // x 128 cols) per pass -> 4 frag stores of 4 kchunks.
        __syncthreads();                  // all waves done reading sbuf
        _Float16* T = &sbuf[0][0] + w * 3072;   // 16 x 136 halves used
        const int kcg0 = (n0 + wn * 128) >> 5;
#pragma unroll
        for (int i = 0; i < 4; ++i) {
#pragma unroll
            for (int j = 0; j < 8; ++j)
#pragma unroll
                for (int r = 0; r < 4; ++r) {
                    float v = acc[i][j][r] + bj[j];
                    v = 1.0f / (1.0f + __expf(-v));   // ACT==0: sigmoid
                    T[(q * 4 + r) * 136 + j * 16 + l15] = (_Float16)v;
                }
            const int mt = mtb_blk + wm * 4 + i;
#pragma unroll
            for (int kci = 0; kci < 4; ++kci) {
                half8 v8 = *(const half8*)(T + l15 * 136 + kci * 32 + q * 8);
                *(half8*)(Ce + ((size_t)mt * 32 + kcg0 + kci) * 512 + lane * 8) = v8;
            }
        }
    }
}

// --------------------------------------- cast x to fp16 frag layout ---------
__global__ __launch_bounds__(256)
void castx_kernel(const float* __restrict__ x, _Float16* __restrict__ xb)
{
    __shared__ _Float16 tile[64 * 72];   // [m-local][k-local]
    const int k0 = blockIdx.x * 64;
    const int m0 = blockIdx.y * 64;
    const int tid = threadIdx.x;
    const int col4 = (tid & 15) * 4;
    const int rb   = tid >> 4;           // 0..15
#pragma unroll
    for (int p = 0; p < 4; ++p) {
        const int row = rb + p * 16;
        float4 a = *(const float4*)(x + (size_t)(m0 + row) * 1024 + k0 + col4);
        _Float16* d = tile + row * 72 + col4;
        d[0] = (_Float16)a.x; d[1] = (_Float16)a.y; d[2] = (_Float16)a.z; d[3] = (_Float16)a.w;
    }
    __syncthreads();
    const int lane = tid & 63, w = tid >> 6;
    const int l15 = lane & 15, q = lane >> 4;
#pragma unroll
    for (int ff = 0; ff < 2; ++ff) {
        const int fidx = w * 2 + ff;
        const int mi = fidx >> 1, kci = fidx & 1;
        half8 v = *(const half8*)(tile + (mi * 16 + l15) * 72 + kci * 32 + q * 8);
        const size_t mt = (m0 >> 4) + mi, kc = (k0 >> 5) + kci;
        *(half8*)(xb + (mt * 32 + kc) * 512 + lane * 8) = v;
    }
}

// ------------- W1/W2 [d][h] fp32 -> frag-major fp16 (n=h, k=d) --------------
// float4 loads; W2 tiles additionally fold the v = W2@Wo partial dot using
// the fp32 registers (full precision), atomicAdd into v (zeroed by zerof).
__global__ __launch_bounds__(256)
void wtr_kernel(const float* __restrict__ W1, const float* __restrict__ W2,
                _Float16* __restrict__ W1F, _Float16* __restrict__ W2F,
                const float* __restrict__ Wo, float* __restrict__ v)
{
    __shared__ _Float16 tile[64 * 73];   // [k-local][n-local], pad 73
    const int z = blockIdx.z;
    const float* src = (z < 16) ? (W1 + (size_t)z * 1048576ull) : (W2 + (size_t)(z - 16) * 1048576ull);
    _Float16*    dst = (z < 16) ? (W1F + (size_t)z * 1048576ull) : (W2F + (size_t)(z - 16) * 1048576ull);
    const int n0 = blockIdx.x * 64;
    const int k0 = blockIdx.y * 64;
    const int tid = threadIdx.x;
    const int lane = tid & 63, w = tid >> 6;
    const int l15 = lane & 15, q = lane >> 4;

    // vectorized load: 4 x float4 per thread (rows w*4+q+p*16, cols l15*4..+3)
    const int col4 = l15 * 4;
    const int rbase = w * 4 + q;
    float4 a4[4];
#pragma unroll
    for (int p = 0; p < 4; ++p) {
        const int row = rbase + p * 16;
        a4[p] = *(const float4*)(src + (size_t)(k0 + row) * 1024 + n0 + col4);
        _Float16* d = tile + row * 73 + col4;
        d[0] = (_Float16)a4[p].x; d[1] = (_Float16)a4[p].y;
        d[2] = (_Float16)a4[p].z; d[3] = (_Float16)a4[p].w;
    }

    if (z >= 16) {
        // v[e][k0+row] += sum_{n-slice} W2[e][k0+row][n0+c] * Wo[e][n0+c]
        const int e = z - 16;
        const float* wo = Wo + ((size_t)e << 10) + n0;
        float* ve = v + ((size_t)e << 10) + k0;
#pragma unroll
        for (int p = 0; p < 4; ++p) {
            float s = a4[p].x * wo[col4] + a4[p].y * wo[col4 + 1]
                    + a4[p].z * wo[col4 + 2] + a4[p].w * wo[col4 + 3];
            s += __shfl_xor(s, 1, 64);
            s += __shfl_xor(s, 2, 64);
            s += __shfl_xor(s, 4, 64);
            s += __shfl_xor(s, 8, 64);
            if (l15 == 0) atomicAdd(&ve[rbase + p * 16], s);
        }
    }

    __syncthreads();
#pragma unroll
    for (int ff = 0; ff < 2; ++ff) {
        const int fidx = w * 2 + ff;
        const int nti = fidx >> 1, kci = fidx & 1;
        half8 hv;
#pragma unroll
        for (int jj = 0; jj < 8; ++jj)
            hv[jj] = tile[(kci * 32 + q * 8 + jj) * 73 + nti * 16 + l15];
        const size_t nt = (n0 >> 4) + nti, kc = (k0 >> 5) + kci;
        *(half8*)(dst + (nt * 32 + kc) * 512 + lane * 8) = hv;
    }
}

// --------------------------- zero f (0.5MB) + v (64KB), contiguous ----------
__global__ __launch_bounds__(256)
void zerof_kernel(float* __restrict__ f)
{
    const size_t i = ((size_t)blockIdx.x * 256 + threadIdx.x) * 4;
    float4 z = {0.f, 0.f, 0.f, 0.f};
    *(float4*)(f + i) = z;
}

// ----------------- bo2[e] = b2[e].Wo[e] + bo[e]  (16 waves) -----------------
__global__ __launch_bounds__(64)
void prep_bo2_kernel(const float* __restrict__ b2, const float* __restrict__ Wo,
                     const float* __restrict__ bo, float* __restrict__ bo2)
{
    const int e = blockIdx.x;
    const int lane = threadIdx.x;
    const float* br = b2 + ((size_t)e << 10);
    const float* wo = Wo + ((size_t)e << 10);
    float s = 0.f;
#pragma unroll
    for (int t = 0; t < 16; ++t) s += br[t * 64 + lane] * wo[t * 64 + lane];
#pragma unroll
    for (int m = 1; m < 64; m <<= 1) s += __shfl_xor(s, m, 64);
    if (lane == 0) bo2[e] = s + bo[e];
}

// ------------------ gates (fp32, full precision) + softmax + combine --------
__global__ __launch_bounds__(256)
void final_kernel(const float* __restrict__ x,
                  const float* __restrict__ Wg1, const float* __restrict__ bg1,
                  const float* __restrict__ Wg2, const float* __restrict__ bg2,
                  const float* __restrict__ f, const float* __restrict__ bo2,
                  float* __restrict__ out)
{
    const int lane = threadIdx.x & 63;
    const int w    = threadIdx.x >> 6;
    const int b    = blockIdx.x * 8 + w * 2;
    const float* xA = x + (size_t)b * 1024;
    const float* xB = xA + 1024;
    float g1A[16], g2A[16], g1B[16], g2B[16];
#pragma unroll
    for (int e = 0; e < 16; ++e) { g1A[e] = 0.f; g2A[e] = 0.f; g1B[e] = 0.f; g2B[e] = 0.f; }
#pragma unroll 2
    for (int t = 0; t < 16; ++t) {
        const int d = t * 64 + lane;
        const float xa = xA[d];
        const float xb2 = xB[d];
        const float4* w1 = (const float4*)(Wg1 + (size_t)d * 16);
        const float4* w2 = (const float4*)(Wg2 + (size_t)d * 16);
#pragma unroll
        for (int q4 = 0; q4 < 4; ++q4) {
            const float4 c1 = w1[q4];
            const float4 c2 = w2[q4];
#pragma unroll
            for (int c = 0; c < 4; ++c) {
                const int e = q4 * 4 + c;
                const float v1 = (c == 0) ? c1.x : (c == 1) ? c1.y : (c == 2) ? c1.z : c1.w;
                const float v2 = (c == 0) ? c2.x : (c == 1) ? c2.y : (c == 2) ? c2.z : c2.w;
                g1A[e] += xa * v1; g1B[e] += xb2 * v1;
                g2A[e] += xa * v2; g2B[e] += xb2 * v2;
            }
        }
    }
#pragma unroll
    for (int e = 0; e < 16; ++e) {
#pragma unroll
        for (int m = 1; m < 64; m <<= 1) {
            g1A[e] += __shfl_xor(g1A[e], m, 64);
            g2A[e] += __shfl_xor(g2A[e], m, 64);
            g1B[e] += __shfl_xor(g1B[e], m, 64);
            g2B[e] += __shfl_xor(g2B[e], m, 64);
        }
    }
    const float* fbA = f + (size_t)b * 16;
    const float* fbB = fbA + 16;
#pragma unroll
    for (int rr = 0; rr < 2; ++rr) {
        const float* gp1 = rr ? g1B : g1A;
        const float* gp2 = rr ? g2B : g2A;
        const float* fb  = rr ? fbB : fbA;
        float a1[16], a2[16], m1 = -1e30f, m2 = -1e30f;
#pragma unroll
        for (int e = 0; e < 16; ++e) {
            a1[e] = gp1[e] + bg1[e]; m1 = fmaxf(m1, a1[e]);
            a2[e] = gp2[e] + bg2[e]; m2 = fmaxf(m2, a2[e]);
        }
        float s1 = 0.f, s2 = 0.f, o1 = 0.f, o2 = 0.f;
#pragma unroll
        for (int e = 0; e < 16; ++e) {
            a1[e] = __expf(a1[e] - m1); s1 += a1[e];
            a2[e] = __expf(a2[e] - m2); s2 += a2[e];
        }
#pragma unroll
        for (int e = 0; e < 16; ++e) {
            const float fe = fb[e] + bo2[e];
            o1 += a1[e] * fe; o2 += a2[e] * fe;
        }
        if (lane == 0) { out[b + rr] = o1 / s1; out[8192 + b + rr] = o2 / s2; }
    }
}

// ----------------------------------------------------------------------------
extern "C" void kernel_launch(void* const* d_in, const int* in_sizes, int n_in,
                              void* d_out, int out_size, void* d_ws, size_t ws_size,
                              hipStream_t stream)
{
    const float* x   = (const float*)d_in[0];
    const float* W1  = (const float*)d_in[1];
    const float* b1  = (const float*)d_in[2];
    const float* W2  = (const float*)d_in[3];
    const float* b2  = (const float*)d_in[4];
    const float* Wo  = (const float*)d_in[5];
    const float* bo  = (const float*)d_in[6];
    const float* Wg1 = (const float*)d_in[7];
    const float* bg1 = (const float*)d_in[8];
    const float* Wg2 = (const float*)d_in[9];
    const float* bg2 = (const float*)d_in[10];
    float* out = (float*)d_out;

    char* ws = (char*)d_ws;
    _Float16* xb  = (_Float16*)(ws);                         // 16 MB (frag)
    _Float16* W1F = (_Float16*)(ws + 16777216ull);           // 32 MB (frag)
    _Float16* W2F = (_Float16*)(ws + 50331648ull);           // 32 MB (frag)
    float*    f   = (float*)   (ws + 83886080ull);           // 0.5 MB
    float*    v   = (float*)   (ws + 84410368ull);           // 64 KB (after f)
    float*    bo2 = (float*)   (ws + 84475904ull);           // 64 B
    char* hbase = ws + 84475968ull;

    int g = 1;
    const int cands[4] = {16, 8, 4, 2};
    for (int ci = 0; ci < 4; ++ci) {
        const size_t need = 84475968ull + (size_t)cands[ci] * 16777216ull;
        if (need <= ws_size) { g = cands[ci]; break; }
    }
    _Float16* h0 = (_Float16*)hbase;

    // zerof covers f (131072 floats) + v (16384 floats), contiguous: 144 blocks
    zerof_kernel<<<144, 256, 0, stream>>>(f);
    castx_kernel<<<dim3(16, 128), 256, 0, stream>>>(x, xb);
    wtr_kernel<<<dim3(16, 16, 32), 256, 0, stream>>>(W1, W2, W1F, W2F, Wo, v);
    prep_bo2_kernel<<<16, 64, 0, stream>>>(b2, Wo, bo, bo2);

    for (int e0 = 0; e0 < 16; e0 += g) {
        gemm_kernel<0><<<dim3(8, 32 * g), 256, 0, stream>>>(
            xb, W1F + (size_t)e0 * 1048576ull, b1 + (size_t)e0 * 1024, h0, 0,
            nullptr, nullptr, 0);
        gemm_kernel<2><<<dim3(8, 32 * g), 256, 0, stream>>>(
            h0, W2F + (size_t)e0 * 1048576ull, b2 + (size_t)e0 * 1024, h0, 8192ull * 1024ull,
            v, f, e0);
    }
    final_kernel<<<1024, 256, 0, stream>>>(x, Wg1, bg1, Wg2, bg2, f, bo2, out);
}